// Round 5
// baseline (191.444 us; speedup 1.0000x reference)
//
#include <hip/hip_runtime.h>

// Problem constants: NTOK=50257, NINP=512, NREL=200, N=1024, L=64, EPS=32
#define NINP 512
#define NREL 200
#define LSEQ 64
#define WT_LD 256           // padded leading dim of transposed W
#define SPB 2               // sequences per fused block
#define NW 8                // waves per block (512 threads)

typedef float vfloat4 __attribute__((ext_vector_type(4)));

// ---------------- Kernel 1: tiled transpose W -> Wt[k][r], fold out-zeroing ----------------
// 32 blocks x 256 threads; 64x64 tile via LDS (+1 pad). Coalesced reads AND writes.
// Block 0 also zeroes out[2] (replaces the separate hipMemsetAsync dispatch).
__global__ __launch_bounds__(256) void wt_kernel(
    const float* __restrict__ W,
    float* __restrict__ Wt,
    float* __restrict__ out)
{
    __shared__ float tile[64][65];
    const int b  = blockIdx.x;          // 0..31
    const int br = b >> 3, bk = b & 7;  // r-tile (4), k-tile (8)
    const int r0 = br * 64, k0 = bk * 64;
    const int t  = threadIdx.x;
    const int ty = t >> 6, tx = t & 63;

    if (b == 0 && t < 2) out[t] = 0.f;

    #pragma unroll
    for (int jj = 0; jj < 16; ++jj) {
        const int i = jj * 4 + ty;                       // row within tile
        tile[i][tx] = (r0 + i < NREL) ? W[(r0 + i) * NINP + k0 + tx] : 0.f;
    }
    __syncthreads();
    #pragma unroll
    for (int jj = 0; jj < 16; ++jj) {
        const int k = k0 + jj * 4 + ty;
        Wt[k * WT_LD + r0 + tx] = tile[tx][jj * 4 + ty]; // stride-65 reads: conflict-free
    }
}

// ---------------- Kernel 2: fused gather + linear + loss ----------------
// grid = N/SPB = 512 blocks x 512 threads -> 2 blocks/CU (37 KB LDS, <=128
// VGPR via __launch_bounds__(512,4)). With SPB=4 there were only 256 blocks
// on 256 CUs (1/CU): Phase B/C ran with the HBM pipe idle chip-wide. Two
// resident blocks let one block's L2/VALU-bound B/C hide under the other's
// HBM-bound gather. nt loads RETAINED (R2 showed cached gather regresses;
// memory-side L3 caches nt traffic anyway).
// Phase A: wave w (= seq s=w>>2, quarter q=w&3) sums 16 rows in 2 batches
//          of 8; NON-TEMPORAL loads. Token indices via wave-uniform scalar
//          loads — no LDS staging, no leading barrier.
// Pack:    WAVE-LOCAL — wave w packs its own Phase-B k-slice [64w,64w+64),
//          one k per lane (2-way-conflict reads = free); pack->B ordering
//          needs only lgkmcnt(0)+sched_barrier, not a block barrier.
// Phase B: wave = kslice (64 k); lane covers 4 relations (float4 Wt).
// Phase C: thread (s=t>>8, r=t&255) sums 8 wave-partials (+bias, loss),
//          block reduction, 2 global atomicAdds.
__global__ __launch_bounds__(512, 4) void fused_kernel(
    const int* __restrict__ seq,
    const float* __restrict__ emb,
    const float* __restrict__ Wt,    // (NINP, WT_LD)
    const int* __restrict__ rel,     // (E,)
    const float* __restrict__ bias,  // (NREL,)
    float* __restrict__ out,         // [2] (zeroed by wt_kernel)
    int N, int eps)
{
    __shared__ vfloat4 hpart[NW][2][64];        // 16 KB  [wave][half][lane]
    __shared__ float2  h_pack2[NINP];           // 4 KB   [k] -> (s0,s1)
    __shared__ float4  pd[NW][SPB][64];         // 16 KB  [wave][s][lane]
    __shared__ unsigned int maskbits[SPB][8];
    __shared__ float   red_lp[NW], red_ac[NW];

    const int i0   = blockIdx.x * SPB;
    const int t    = threadIdx.x;
    const int wave = __builtin_amdgcn_readfirstlane(t >> 6);
    const int lane = t & 63;

    // ---- maskbits: wave 0 only, before Phase A; in-wave DS ordering makes
    //      zero -> atomicOr safe without a barrier. Guarded for Phase C by bar2.
    if (wave == 0) {
        if (lane < SPB * 8) ((unsigned int*)maskbits)[lane] = 0u;
        const int s = lane >> 5, j = lane & 31;       // 64 lanes = 2 seq x 32 edges
        if (j < eps) {
            int r = rel[(i0 + s) * eps + j];
            atomicOr(&maskbits[s][r >> 5], 1u << (r & 31));
        }
    }

    // ---- Phase A: gather 16 rows per wave, 8-row batches, nt loads ----
    {
        const int sq = wave >> 2, qq = wave & 3;
        const int* sp = seq + (long)(i0 + sq) * LSEQ + qq * 16;  // wave-uniform base
        vfloat4 lo = (vfloat4)0.f;
        vfloat4 hi = (vfloat4)0.f;
        #pragma unroll
        for (int j0 = 0; j0 < 16; j0 += 8) {
            const vfloat4* rp[8];
            #pragma unroll
            for (int j = 0; j < 8; ++j)
                rp[j] = (const vfloat4*)(emb +
                    (long)__builtin_amdgcn_readfirstlane(sp[j0 + j]) * NINP);
            vfloat4 l[8], h[8];
            #pragma unroll
            for (int j = 0; j < 8; ++j) {
                l[j] = __builtin_nontemporal_load(rp[j] + lane);
                h[j] = __builtin_nontemporal_load(rp[j] + 64 + lane);
            }
            #pragma unroll
            for (int j = 0; j < 4; ++j) {        // pairwise tree, retire early
                l[j] = l[2*j] + l[2*j+1];
                h[j] = h[2*j] + h[2*j+1];
            }
            lo += (l[0] + l[1]) + (l[2] + l[3]);
            hi += (h[0] + h[1]) + (h[2] + h[3]);
        }
        hpart[wave][0][lane] = lo;
        hpart[wave][1][lane] = hi;
    }
    __syncthreads();   // bar1: hpart ready (pack reads cross-wave)

    // ---- Wave-local pack: lane packs k = 64*wave + lane ----
    {
        const int k = wave * 64 + lane;
        const int fg = k >> 2, c = k & 3;
        const int half = fg >> 6, fl = fg & 63;
        float2 v;
        #pragma unroll
        for (int s = 0; s < SPB; ++s) {
            float sum = 0.f;
            #pragma unroll
            for (int q = 0; q < 4; ++q)
                sum += ((const float*)&hpart[s * 4 + q][half][fl])[c];
            ((float*)&v)[s] = sum;
        }
        h_pack2[k] = v;
    }
    // same-wave LDS produce->consume: in-order DS pipe, just drain lgkmcnt.
    asm volatile("s_waitcnt lgkmcnt(0)" ::: "memory");
    __builtin_amdgcn_sched_barrier(0);        // keep reads below the waitcnt (rule #18)

    // ---- Phase B: partial dots (wave's own k-slice, packed above) ----
    {
        const float4* Wt4 = (const float4*)Wt;     // [k][64]
        float4 a0 = make_float4(0.f, 0.f, 0.f, 0.f);
        float4 a1 = a0;                            // acc[s] over 4 relations
        const int kbase = wave * 64;
        #pragma unroll 4
        for (int k = kbase; k < kbase + 64; ++k) {
            const float4 wv = Wt4[k * 64 + lane];  // coalesced 1KB, L2-resident
            const float2 hp = h_pack2[k];          // broadcast ds_read_b64
            a0.x += hp.x * wv.x; a0.y += hp.x * wv.y; a0.z += hp.x * wv.z; a0.w += hp.x * wv.w;
            a1.x += hp.y * wv.x; a1.y += hp.y * wv.y; a1.z += hp.y * wv.z; a1.w += hp.y * wv.w;
        }
        pd[wave][0][lane] = a0;
        pd[wave][1][lane] = a1;
    }
    __syncthreads();   // bar2: pd + maskbits ready for Phase C

    // ---- Phase C: reduce partials, loss terms, block reduction ----
    float term = 0.f, match = 0.f;
    {
        const int s = t >> 8;        // 0..1
        const int r = t & 255;       // 0..255
        if (r < NREL) {
            const int f = r >> 2, c = r & 3;
            float dot = bias[r];
            #pragma unroll
            for (int w = 0; w < NW; ++w)
                dot += ((const float*)&pd[w][s][f])[c];   // word idx == r: conflict-free
            const unsigned mb = (maskbits[s][r >> 5] >> (r & 31)) & 1u;
            if (mb) {
                term = fminf(dot, 0.f) - log1pf(expf(-fabsf(dot)));  // log_sigmoid
            } else {
                term = logf(1e-5f + 1.f / (1.f + expf(dot)));        // log(1e-5+sig(-x))
            }
            match = (((dot > 0.5f) ? 1u : 0u) == mb) ? 1.f : 0.f;
        }
    }

    #pragma unroll
    for (int off = 32; off > 0; off >>= 1) {
        term  += __shfl_down(term,  off);
        match += __shfl_down(match, off);
    }
    if (lane == 0) { red_lp[wave] = term; red_ac[wave] = match; }
    __syncthreads();
    if (t == 0) {
        float s = 0.f, a = 0.f;
        #pragma unroll
        for (int w = 0; w < NW; ++w) { s += red_lp[w]; a += red_ac[w]; }
        atomicAdd(out + 0, s / (float)N);
        atomicAdd(out + 1, a / ((float)N * (float)NREL));
    }
}

extern "C" void kernel_launch(void* const* d_in, const int* in_sizes, int n_in,
                              void* d_out, int out_size, void* d_ws, size_t ws_size,
                              hipStream_t stream) {
    const int*   seq = (const int*)d_in[0];
    const int*   m   = (const int*)d_in[1]; (void)m;
    const int*   rel = (const int*)d_in[2];
    const float* emb = (const float*)d_in[3];
    const float* W   = (const float*)d_in[4];
    const float* b   = (const float*)d_in[5];
    float* out = (float*)d_out;

    const int N   = in_sizes[1];               // 1024
    const int eps = in_sizes[2] / N;           // 32

    float* Wt = (float*)d_ws;                  // 512 KB

    wt_kernel<<<32, 256, 0, stream>>>(W, Wt, out);   // also zeroes out[2]
    fused_kernel<<<N / SPB, 512, 0, stream>>>(seq, emb, Wt, rel, b, out, N, eps);
}

// Round 6
// 175.448 us; speedup vs baseline: 1.0912x; 1.0912x over previous
//
#include <hip/hip_runtime.h>

// Problem constants: NTOK=50257, NINP=512, NREL=200, N=1024, L=64, EPS=32
#define NINP 512
#define NREL 200
#define LSEQ 64
#define WT_LD 256           // padded leading dim of transposed W
#define SPB 4               // sequences per fused block
#define NW 16               // waves per block (1024 threads)

typedef float vfloat4 __attribute__((ext_vector_type(4)));

// ---------------- Kernel 1: tiled transpose W -> Wt[k][r], fold out-zeroing ----------------
// 32 blocks x 256 threads; 64x64 tile via LDS (+1 pad). Coalesced reads AND writes.
// Block 0 also zeroes out[2] (replaces the separate hipMemsetAsync dispatch).
__global__ __launch_bounds__(256) void wt_kernel(
    const float* __restrict__ W,
    float* __restrict__ Wt,
    float* __restrict__ out)
{
    __shared__ float tile[64][65];
    const int b  = blockIdx.x;          // 0..31
    const int br = b >> 3, bk = b & 7;  // r-tile (4), k-tile (8)
    const int r0 = br * 64, k0 = bk * 64;
    const int t  = threadIdx.x;
    const int ty = t >> 6, tx = t & 63;

    if (b == 0 && t < 2) out[t] = 0.f;

    #pragma unroll
    for (int jj = 0; jj < 16; ++jj) {
        const int i = jj * 4 + ty;                       // row within tile
        tile[i][tx] = (r0 + i < NREL) ? W[(r0 + i) * NINP + k0 + tx] : 0.f;
    }
    __syncthreads();
    #pragma unroll
    for (int jj = 0; jj < 16; ++jj) {
        const int k = k0 + jj * 4 + ty;
        Wt[k * WT_LD + r0 + tx] = tile[tx][jj * 4 + ty]; // stride-65 reads: conflict-free
    }
}

// ---------------- Kernel 2: fused gather + linear + loss ----------------
// grid = N/SPB = 256 blocks x 1024 threads (1 block/CU, 16 waves) — proven core.
// R5 falsified the SPB=2 overlap theory (+20.8 us); SPB=4 retained.
// Phase A: wave w (= seq s=w>>2, quarter q=w&3) sums 16 rows in 2 batches of 8;
//          CACHED loads (R2/R5 deconfound: cached beats nt by ~13 us — the nt
//          hint bypasses Infinity-Cache allocation, so the ~44% repeated rows
//          (59 MB) re-hit HBM instead of L3; emb's 103 MB fits L3 entirely).
//          Token indices via wave-uniform scalar loads — no LDS staging barrier.
// Pack:    WAVE-LOCAL — wave w packs its own Phase-B slice k in [32w,32w+32)
//          into h_pack4[k]; pack->B needs only lgkmcnt(0)+sched_barrier.
// Phase B: wave = kslice (32 k); lane covers 4 relations (float4 Wt).
// Phase C: thread (s=t>>8, r=t&255) sums 16 wave-partials (+bias, loss),
//          block reduction, 2 global atomicAdds.
__global__ __launch_bounds__(1024) void fused_kernel(
    const int* __restrict__ seq,
    const float* __restrict__ emb,
    const float* __restrict__ Wt,    // (NINP, WT_LD)
    const int* __restrict__ rel,     // (E,)
    const float* __restrict__ bias,  // (NREL,)
    float* __restrict__ out,         // [2] (zeroed by wt_kernel)
    int N, int eps)
{
    __shared__ vfloat4 hpart[NW][2][64];        // 32 KB  [wave][half][lane]
    __shared__ float4  h_pack4[NINP];           // 8 KB   [k] -> (s0,s1,s2,s3)
    __shared__ float4  pd[NW][SPB][64];         // 64 KB  [wave][s][lane]
    __shared__ unsigned int maskbits[SPB][8];
    __shared__ float   red_lp[NW], red_ac[NW];

    const int i0   = blockIdx.x * SPB;
    const int t    = threadIdx.x;
    const int wave = __builtin_amdgcn_readfirstlane(t >> 6);
    const int lane = t & 63;

    if (t < SPB * 8) ((unsigned int*)maskbits)[t] = 0u;

    // ---- Phase A: gather 16 rows per wave, 8-row batches, cached loads ----
    {
        const int sq = wave >> 2, qq = wave & 3;
        const int* sp = seq + (long)(i0 + sq) * LSEQ + qq * 16;  // wave-uniform base
        vfloat4 lo = (vfloat4)0.f;
        vfloat4 hi = (vfloat4)0.f;
        #pragma unroll
        for (int j0 = 0; j0 < 16; j0 += 8) {
            const vfloat4* rp[8];
            #pragma unroll
            for (int j = 0; j < 8; ++j)
                rp[j] = (const vfloat4*)(emb +
                    (long)__builtin_amdgcn_readfirstlane(sp[j0 + j]) * NINP);
            vfloat4 l[8], h[8];
            #pragma unroll
            for (int j = 0; j < 8; ++j) {
                l[j] = rp[j][lane];
                h[j] = rp[j][64 + lane];
            }
            #pragma unroll
            for (int j = 0; j < 4; ++j) {        // pairwise tree, retire early
                l[j] = l[2*j] + l[2*j+1];
                h[j] = h[2*j] + h[2*j+1];
            }
            lo += (l[0] + l[1]) + (l[2] + l[3]);
            hi += (h[0] + h[1]) + (h[2] + h[3]);
        }
        hpart[wave][0][lane] = lo;
        hpart[wave][1][lane] = hi;
    }
    __syncthreads();   // bar1: hpart ready for cross-wave pack; maskbits zero'd

    if (t < SPB * 32) {
        const int s = t >> 5, j = t & 31;
        if (j < eps) {
            int r = rel[(i0 + s) * eps + j];
            atomicOr(&maskbits[s][r >> 5], 1u << (r & 31));
        }
    }

    // ---- Wave-local pack: h_pack4[k] for k in [32*wave, 32*wave+32) ----
    {
        const int kbase = wave * 32;
        const int p = lane >> 5;              // 0 -> s{0,1}, 1 -> s{2,3}
        const int k = kbase + (lane & 31);
        const int fg = k >> 2, c = k & 3;
        const int half = fg >> 6, fl = fg & 63;
        float2 v;
        #pragma unroll
        for (int d = 0; d < 2; ++d) {
            const int sbar = 2 * p + d;
            float sum = 0.f;
            #pragma unroll
            for (int q = 0; q < 4; ++q)
                sum += ((const float*)&hpart[sbar * 4 + q][half][fl])[c];
            ((float*)&v)[d] = sum;
        }
        ((float2*)&h_pack4[k])[p] = v;
    }
    // same-wave LDS produce->consume: in-order DS pipe, just drain lgkmcnt.
    asm volatile("s_waitcnt lgkmcnt(0)" ::: "memory");
    __builtin_amdgcn_sched_barrier(0);        // keep reads below the waitcnt (rule #18)

    // ---- Phase B: partial dots (wave's own k-slice, packed above) ----
    {
        const float4* Wt4 = (const float4*)Wt;     // [k][64]
        float4 a0 = make_float4(0.f, 0.f, 0.f, 0.f);
        float4 a1 = a0, a2 = a0, a3 = a0;          // acc[s] over 4 relations
        const int kbase = wave * 32;
        #pragma unroll 4
        for (int k = kbase; k < kbase + 32; ++k) {
            const float4 wv = Wt4[k * 64 + lane];  // coalesced 1KB, L2-resident
            const float4 hp = h_pack4[k];          // broadcast ds_read_b128
            a0.x += hp.x * wv.x; a0.y += hp.x * wv.y; a0.z += hp.x * wv.z; a0.w += hp.x * wv.w;
            a1.x += hp.y * wv.x; a1.y += hp.y * wv.y; a1.z += hp.y * wv.z; a1.w += hp.y * wv.w;
            a2.x += hp.z * wv.x; a2.y += hp.z * wv.y; a2.z += hp.z * wv.z; a2.w += hp.z * wv.w;
            a3.x += hp.w * wv.x; a3.y += hp.w * wv.y; a3.z += hp.w * wv.z; a3.w += hp.w * wv.w;
        }
        pd[wave][0][lane] = a0;
        pd[wave][1][lane] = a1;
        pd[wave][2][lane] = a2;
        pd[wave][3][lane] = a3;
    }
    __syncthreads();   // bar2: pd + maskbits ready for Phase C

    // ---- Phase C: reduce partials, loss terms, block reduction ----
    float term = 0.f, match = 0.f;
    {
        const int s = t >> 8;        // 0..3
        const int r = t & 255;       // 0..255
        if (r < NREL) {
            const int f = r >> 2, c = r & 3;
            float dot = bias[r];
            #pragma unroll
            for (int w = 0; w < NW; ++w)
                dot += ((const float*)&pd[w][s][f])[c];   // word idx == r: conflict-free
            const unsigned mb = (maskbits[s][r >> 5] >> (r & 31)) & 1u;
            if (mb) {
                term = fminf(dot, 0.f) - log1pf(expf(-fabsf(dot)));  // log_sigmoid
            } else {
                term = logf(1e-5f + 1.f / (1.f + expf(dot)));        // log(1e-5+sig(-x))
            }
            match = (((dot > 0.5f) ? 1u : 0u) == mb) ? 1.f : 0.f;
        }
    }

    #pragma unroll
    for (int off = 32; off > 0; off >>= 1) {
        term  += __shfl_down(term,  off);
        match += __shfl_down(match, off);
    }
    if (lane == 0) { red_lp[wave] = term; red_ac[wave] = match; }
    __syncthreads();
    if (t == 0) {
        float s = 0.f, a = 0.f;
        #pragma unroll
        for (int w = 0; w < NW; ++w) { s += red_lp[w]; a += red_ac[w]; }
        atomicAdd(out + 0, s / (float)N);
        atomicAdd(out + 1, a / ((float)N * (float)NREL));
    }
}

extern "C" void kernel_launch(void* const* d_in, const int* in_sizes, int n_in,
                              void* d_out, int out_size, void* d_ws, size_t ws_size,
                              hipStream_t stream) {
    const int*   seq = (const int*)d_in[0];
    const int*   m   = (const int*)d_in[1]; (void)m;
    const int*   rel = (const int*)d_in[2];
    const float* emb = (const float*)d_in[3];
    const float* W   = (const float*)d_in[4];
    const float* b   = (const float*)d_in[5];
    float* out = (float*)d_out;

    const int N   = in_sizes[1];               // 1024
    const int eps = in_sizes[2] / N;           // 32

    float* Wt = (float*)d_ws;                  // 512 KB

    wt_kernel<<<32, 256, 0, stream>>>(W, Wt, out);   // also zeroes out[2]
    fused_kernel<<<N / SPB, 1024, 0, stream>>>(seq, emb, Wt, rel, b, out, N, eps);
}

// Round 7
// 172.067 us; speedup vs baseline: 1.1126x; 1.0197x over previous
//
#include <hip/hip_runtime.h>

// Problem constants: NTOK=50257, NINP=512, NREL=200, N=1024, L=64, EPS=32
#define NINP 512
#define NREL 200
#define LSEQ 64
#define WT_LD 256           // padded leading dim of transposed W
#define SPB 4               // sequences per fused block
#define NW 16               // waves per block (1024 threads)

typedef float vfloat4 __attribute__((ext_vector_type(4)));

// ---------------- Kernel 1: tiled transpose W -> Wt[k][r], fold out-zeroing ----------------
// 32 blocks x 256 threads; 64x64 tile via LDS (+1 pad). Coalesced reads AND writes.
// Block 0 also zeroes out[2] (replaces the separate hipMemsetAsync dispatch).
__global__ __launch_bounds__(256) void wt_kernel(
    const float* __restrict__ W,
    float* __restrict__ Wt,
    float* __restrict__ out)
{
    __shared__ float tile[64][65];
    const int b  = blockIdx.x;          // 0..31
    const int br = b >> 3, bk = b & 7;  // r-tile (4), k-tile (8)
    const int r0 = br * 64, k0 = bk * 64;
    const int t  = threadIdx.x;
    const int ty = t >> 6, tx = t & 63;

    if (b == 0 && t < 2) out[t] = 0.f;

    #pragma unroll
    for (int jj = 0; jj < 16; ++jj) {
        const int i = jj * 4 + ty;                       // row within tile
        tile[i][tx] = (r0 + i < NREL) ? W[(r0 + i) * NINP + k0 + tx] : 0.f;
    }
    __syncthreads();
    #pragma unroll
    for (int jj = 0; jj < 16; ++jj) {
        const int k = k0 + jj * 4 + ty;
        Wt[k * WT_LD + r0 + tx] = tile[tx][jj * 4 + ty]; // stride-65 reads: conflict-free
    }
}

// ---------------- Kernel 2: fused gather + linear + loss ----------------
// grid = N/SPB = 256 blocks x 1024 threads (1 block/CU, 16 waves) — proven core.
// Factorial over {SPB,cache-policy} (R0,R2,R3,R5,R6): SPB=4 + nt is best.
// nt RETAINED: at 1 block/CU the gather's 128 MB stream pollutes L1/L2 when
// cached (+4.8 us, R6); L3 reuse of repeated rows does not pay for it.
// Phase A: wave w (= seq s=w>>2, quarter q=w&3) sums 16 rows in 2 batches of 8;
//          NON-TEMPORAL loads. Token indices via wave-uniform scalar loads —
//          no LDS staging, no leading barrier.
// Pack:    WAVE-LOCAL — wave w packs exactly its own Phase-B slice k in [32w,32w+32)
//          into h_pack4[k]; pack->B ordering needs only lgkmcnt(0)+sched_barrier
//          (same-wave LDS in-order), not a block barrier.
// Phase B: wave = kslice (32 k); lane covers 4 relations (float4 Wt).
// Phase C: thread (s=t>>8, r=t&255) sums 16 wave-partials (+bias, loss),
//          block reduction, 2 global atomicAdds.
__global__ __launch_bounds__(1024) void fused_kernel(
    const int* __restrict__ seq,
    const float* __restrict__ emb,
    const float* __restrict__ Wt,    // (NINP, WT_LD)
    const int* __restrict__ rel,     // (E,)
    const float* __restrict__ bias,  // (NREL,)
    float* __restrict__ out,         // [2] (zeroed by wt_kernel)
    int N, int eps)
{
    __shared__ vfloat4 hpart[NW][2][64];        // 32 KB  [wave][half][lane]
    __shared__ float4  h_pack4[NINP];           // 8 KB   [k] -> (s0,s1,s2,s3)
    __shared__ float4  pd[NW][SPB][64];         // 64 KB  [wave][s][lane]
    __shared__ unsigned int maskbits[SPB][8];
    __shared__ float   red_lp[NW], red_ac[NW];

    const int i0   = blockIdx.x * SPB;
    const int t    = threadIdx.x;
    const int wave = __builtin_amdgcn_readfirstlane(t >> 6);
    const int lane = t & 63;

    if (t < SPB * 8) ((unsigned int*)maskbits)[t] = 0u;

    // ---- Phase A: gather 16 rows per wave, 8-row batches, nt loads ----
    {
        const int sq = wave >> 2, qq = wave & 3;
        const int* sp = seq + (long)(i0 + sq) * LSEQ + qq * 16;  // wave-uniform base
        vfloat4 lo = (vfloat4)0.f;
        vfloat4 hi = (vfloat4)0.f;
        #pragma unroll
        for (int j0 = 0; j0 < 16; j0 += 8) {
            const vfloat4* rp[8];
            #pragma unroll
            for (int j = 0; j < 8; ++j)
                rp[j] = (const vfloat4*)(emb +
                    (long)__builtin_amdgcn_readfirstlane(sp[j0 + j]) * NINP);
            vfloat4 l[8], h[8];
            #pragma unroll
            for (int j = 0; j < 8; ++j) {
                l[j] = __builtin_nontemporal_load(rp[j] + lane);
                h[j] = __builtin_nontemporal_load(rp[j] + 64 + lane);
            }
            #pragma unroll
            for (int j = 0; j < 4; ++j) {        // pairwise tree, retire early
                l[j] = l[2*j] + l[2*j+1];
                h[j] = h[2*j] + h[2*j+1];
            }
            lo += (l[0] + l[1]) + (l[2] + l[3]);
            hi += (h[0] + h[1]) + (h[2] + h[3]);
        }
        hpart[wave][0][lane] = lo;
        hpart[wave][1][lane] = hi;
    }
    __syncthreads();   // bar1: hpart ready for cross-wave pack; maskbits zero'd

    if (t < SPB * 32) {
        const int s = t >> 5, j = t & 31;
        if (j < eps) {
            int r = rel[(i0 + s) * eps + j];
            atomicOr(&maskbits[s][r >> 5], 1u << (r & 31));
        }
    }

    // ---- Wave-local pack: h_pack4[k] for k in [32*wave, 32*wave+32) ----
    {
        const int kbase = wave * 32;
        const int p = lane >> 5;              // 0 -> s{0,1}, 1 -> s{2,3}
        const int k = kbase + (lane & 31);
        const int fg = k >> 2, c = k & 3;
        const int half = fg >> 6, fl = fg & 63;
        float2 v;
        #pragma unroll
        for (int d = 0; d < 2; ++d) {
            const int sbar = 2 * p + d;
            float sum = 0.f;
            #pragma unroll
            for (int q = 0; q < 4; ++q)
                sum += ((const float*)&hpart[sbar * 4 + q][half][fl])[c];
            ((float*)&v)[d] = sum;
        }
        ((float2*)&h_pack4[k])[p] = v;
    }
    // same-wave LDS produce->consume: in-order DS pipe, just drain lgkmcnt.
    asm volatile("s_waitcnt lgkmcnt(0)" ::: "memory");
    __builtin_amdgcn_sched_barrier(0);        // keep reads below the waitcnt (rule #18)

    // ---- Phase B: partial dots (wave's own k-slice, packed above) ----
    {
        const float4* Wt4 = (const float4*)Wt;     // [k][64]
        float4 a0 = make_float4(0.f, 0.f, 0.f, 0.f);
        float4 a1 = a0, a2 = a0, a3 = a0;          // acc[s] over 4 relations
        const int kbase = wave * 32;
        #pragma unroll 4
        for (int k = kbase; k < kbase + 32; ++k) {
            const float4 wv = Wt4[k * 64 + lane];  // coalesced 1KB, L2-resident
            const float4 hp = h_pack4[k];          // broadcast ds_read_b128
            a0.x += hp.x * wv.x; a0.y += hp.x * wv.y; a0.z += hp.x * wv.z; a0.w += hp.x * wv.w;
            a1.x += hp.y * wv.x; a1.y += hp.y * wv.y; a1.z += hp.y * wv.z; a1.w += hp.y * wv.w;
            a2.x += hp.z * wv.x; a2.y += hp.z * wv.y; a2.z += hp.z * wv.z; a2.w += hp.z * wv.w;
            a3.x += hp.w * wv.x; a3.y += hp.w * wv.y; a3.z += hp.w * wv.z; a3.w += hp.w * wv.w;
        }
        pd[wave][0][lane] = a0;
        pd[wave][1][lane] = a1;
        pd[wave][2][lane] = a2;
        pd[wave][3][lane] = a3;
    }
    __syncthreads();   // bar2: pd + maskbits ready for Phase C

    // ---- Phase C: reduce partials, loss terms, block reduction ----
    float term = 0.f, match = 0.f;
    {
        const int s = t >> 8;        // 0..3
        const int r = t & 255;       // 0..255
        if (r < NREL) {
            const int f = r >> 2, c = r & 3;
            float dot = bias[r];
            #pragma unroll
            for (int w = 0; w < NW; ++w)
                dot += ((const float*)&pd[w][s][f])[c];   // word idx == r: conflict-free
            const unsigned mb = (maskbits[s][r >> 5] >> (r & 31)) & 1u;
            if (mb) {
                term = fminf(dot, 0.f) - log1pf(expf(-fabsf(dot)));  // log_sigmoid
            } else {
                term = logf(1e-5f + 1.f / (1.f + expf(dot)));        // log(1e-5+sig(-x))
            }
            match = (((dot > 0.5f) ? 1u : 0u) == mb) ? 1.f : 0.f;
        }
    }

    #pragma unroll
    for (int off = 32; off > 0; off >>= 1) {
        term  += __shfl_down(term,  off);
        match += __shfl_down(match, off);
    }
    if (lane == 0) { red_lp[wave] = term; red_ac[wave] = match; }
    __syncthreads();
    if (t == 0) {
        float s = 0.f, a = 0.f;
        #pragma unroll
        for (int w = 0; w < NW; ++w) { s += red_lp[w]; a += red_ac[w]; }
        atomicAdd(out + 0, s / (float)N);
        atomicAdd(out + 1, a / ((float)N * (float)NREL));
    }
}

extern "C" void kernel_launch(void* const* d_in, const int* in_sizes, int n_in,
                              void* d_out, int out_size, void* d_ws, size_t ws_size,
                              hipStream_t stream) {
    const int*   seq = (const int*)d_in[0];
    const int*   m   = (const int*)d_in[1]; (void)m;
    const int*   rel = (const int*)d_in[2];
    const float* emb = (const float*)d_in[3];
    const float* W   = (const float*)d_in[4];
    const float* b   = (const float*)d_in[5];
    float* out = (float*)d_out;

    const int N   = in_sizes[1];               // 1024
    const int eps = in_sizes[2] / N;           // 32

    float* Wt = (float*)d_ws;                  // 512 KB

    wt_kernel<<<32, 256, 0, stream>>>(W, Wt, out);   // also zeroes out[2]
    fused_kernel<<<N / SPB, 1024, 0, stream>>>(seq, emb, Wt, rel, b, out, N, eps);
}